// Round 6
// baseline (240.600 us; speedup 1.0000x reference)
//
#include <hip/hip_runtime.h>
#include <stdint.h>

#define BB 32
#define TT 1024
#define CC 384
#define MAXMEL 4096

typedef float f4 __attribute__((ext_vector_type(4)));  // native vec4 for nt builtins

// Single fused kernel. Grid (MAXMEL/32, BB), 512 threads.
// Each block: (1) scans its batch's 1024 durations (2 elems/thread, shuffle
// scan, dur row is L2-resident so the redundancy is ~free), (2) for each of
// its 32 frames, upper_bound-searches the LDS cumsum, (3) copies the token
// row as 3 nontemporal float4 per lane (32 lanes/frame), zeros if invalid.
__global__ __launch_bounds__(512) void lr_fused(const float* __restrict__ x,
                                                const int* __restrict__ dur,
                                                float* __restrict__ out,
                                                float* __restrict__ out_total) {
    __shared__ int s_cs[TT];
    __shared__ int s_wsum[8];
    const int b = blockIdx.y;
    const int tid = threadIdx.x;
    const int lane64 = tid & 63;
    const int wid = tid >> 6;  // 8 waves

    // ---- scan: 2 elements per thread ----
    const int2 d = ((const int2*)(dur + b * TT))[tid];
    const int pair = d.x + d.y;
    int inc = pair;
    #pragma unroll
    for (int off = 1; off < 64; off <<= 1) {
        int n = __shfl_up(inc, off, 64);
        if (lane64 >= off) inc += n;
    }
    if (lane64 == 63) s_wsum[wid] = inc;
    __syncthreads();
    if (wid == 0 && lane64 < 8) {
        int w = s_wsum[lane64];
        #pragma unroll
        for (int off = 1; off < 8; off <<= 1) {
            int n = __shfl_up(w, off, 64);
            if (lane64 >= off) w += n;
        }
        s_wsum[lane64] = w;
    }
    __syncthreads();
    int excl = inc - pair + (wid > 0 ? s_wsum[wid - 1] : 0);
    s_cs[2 * tid]     = excl + d.x;
    s_cs[2 * tid + 1] = excl + pair;
    __syncthreads();

    const int total = s_cs[TT - 1];
    if (blockIdx.x == 0 && tid == 0) out_total[b] = (float)total;

    // ---- expand: 2 frame-groups of 16 frames, 32 lanes/frame ----
    const int lane32 = tid & 31;
    const int fsub = tid >> 5;  // 0..15
    #pragma unroll
    for (int g = 0; g < 2; ++g) {
        const int frame = blockIdx.x * 32 + g * 16 + fsub;
        f4* outp = (f4*)(out + ((size_t)b * MAXMEL + frame) * CC);
        if (frame < total) {
            int lo = 0, hi = TT;
            while (lo < hi) {
                int mid = (lo + hi) >> 1;
                if (s_cs[mid] <= frame) lo = mid + 1; else hi = mid;
            }
            const int t = min(lo, TT - 1);
            const f4* src = (const f4*)(x + ((size_t)b * TT + t) * CC);
            #pragma unroll
            for (int k = 0; k < 3; ++k) {
                f4 v = src[lane32 + k * 32];
                __builtin_nontemporal_store(v, &outp[lane32 + k * 32]);
            }
        } else {
            const f4 z = {0.f, 0.f, 0.f, 0.f};
            #pragma unroll
            for (int k = 0; k < 3; ++k)
                __builtin_nontemporal_store(z, &outp[lane32 + k * 32]);
        }
    }
}

extern "C" void kernel_launch(void* const* d_in, const int* in_sizes, int n_in,
                              void* d_out, int out_size, void* d_ws, size_t ws_size,
                              hipStream_t stream) {
    const float* x = (const float*)d_in[0];
    const int* dur = (const int*)d_in[1];  // reference int64 -> int32 on device per harness
    float* out = (float*)d_out;
    float* out_total = out + (size_t)BB * MAXMEL * CC;  // 32 floats at the tail
    lr_fused<<<dim3(MAXMEL / 32, BB), 512, 0, stream>>>(x, dur, out, out_total);
}